// Round 4
// baseline (913.165 us; speedup 1.0000x reference)
//
#include <hip/hip_runtime.h>
#include <math.h>

#define NN 50000
#define NE 640000
#define F  32
#define KCH 9
#define CUT 5.0f

#define C13 (1.0f/3.0f)
#define C23 (2.0f/3.0f)
#define C15 0.2f
#define C25 0.4f
#define C17 (1.0f/7.0f)
#define C27 (2.0f/7.0f)
#define IS3 0.5773502691896258f   /* 1/sqrt(3) */
#define S35 0.3464101615137755f   /* sqrt(3)/5 */
#define S37 0.2474358296526968f   /* sqrt(3)/7 */
#define S3  1.7320508075688772f

__global__ __launch_bounds__(256) void init_x(const float* __restrict__ embed,
                                              const int* __restrict__ Z,
                                              float* __restrict__ x) {
    int idx = blockIdx.x * 256 + threadIdx.x;   // n*32 + f
    if (idx >= NN * F) return;
    int n = idx >> 5, f = idx & 31;
    float v = embed[Z[n] * F + f];
    float* xp = x + (size_t)n * KCH * F + f;
    xp[0] = v;
    #pragma unroll
    for (int a = 1; a < KCH; ++a) xp[a * F] = 0.f;
}

// count only LIVE edges (r < CUT, not self). Filter expression must match fill_kernel.
__global__ __launch_bounds__(256) void hist_kernel(const int* __restrict__ idx_i,
                                                   const int* __restrict__ idx_j,
                                                   const float* __restrict__ dr,
                                                   int* __restrict__ cnt) {
    int e = blockIdx.x * 256 + threadIdx.x;
    if (e >= NE) return;
    int ni = idx_i[e], nj = idx_j[e];
    float dx = dr[3 * e + 0], dy = dr[3 * e + 1], dz = dr[3 * e + 2];
    float r2 = fmaf(dx, dx, fmaf(dy, dy, dz * dz));
    if (ni != nj && r2 < CUT * CUT) atomicAdd(&cnt[ni], 1);
}

#define SCAN_T 1024
#define SCAN_C ((NN + SCAN_T - 1) / SCAN_T)   // 49

__global__ __launch_bounds__(SCAN_T) void scan_kernel(const int* __restrict__ cnt,
                                                      int* __restrict__ offs,
                                                      int* __restrict__ head) {
    __shared__ int ps[SCAN_T];
    int t = threadIdx.x;
    int b = t * SCAN_C;
    int e = min(b + SCAN_C, NN);
    int s = 0;
    for (int i = b; i < e; ++i) s += cnt[i];
    ps[t] = s;
    __syncthreads();
    for (int off = 1; off < SCAN_T; off <<= 1) {
        int v = (t >= off) ? ps[t - off] : 0;
        __syncthreads();
        ps[t] += v;
        __syncthreads();
    }
    int run = (t == 0) ? 0 : ps[t - 1];
    for (int i = b; i < e; ++i) { int c = cnt[i]; offs[i] = run; head[i] = run; run += c; }
    if (t == SCAN_T - 1) offs[NN] = ps[SCAN_T - 1];
}

// compact live edges + precompute geometry:
// gA = {ux, uy, uz, bits(nj)}, gB = {rc0..rc3}, gC = {rc4..rc7}  (rc = rad*cut)
__global__ __launch_bounds__(256) void fill_kernel(const int* __restrict__ idx_i,
                                                   const int* __restrict__ idx_j,
                                                   const float* __restrict__ dr,
                                                   int* __restrict__ head,
                                                   float4* __restrict__ geo) {
    int e = blockIdx.x * 256 + threadIdx.x;
    if (e >= NE) return;
    int ni = idx_i[e], nj = idx_j[e];
    float dx = dr[3 * e + 0], dy = dr[3 * e + 1], dz = dr[3 * e + 2];
    float r2 = fmaf(dx, dx, fmaf(dy, dy, dz * dz));
    if (!(ni != nj && r2 < CUT * CUT)) return;

    float r = sqrtf(r2);
    float inv = 1.0f / fmaxf(r, 1e-9f);
    float ux = dx * inv, uy = dy * inv, uz = dz * inv;

    float cut = expf(-r2 / fmaxf(CUT * CUT - r2, 1e-12f));
    float ur = r / (1.0f + r), vr = 1.0f - ur;
    float up2 = ur * ur,  up3 = up2 * ur, up4 = up3 * ur, up5 = up4 * ur, up6 = up5 * ur, up7 = up6 * ur;
    float vp2 = vr * vr,  vp3 = vp2 * vr, vp4 = vp3 * vr, vp5 = vp4 * vr, vp6 = vp5 * vr, vp7 = vp6 * vr;

    int p = atomicAdd(&head[ni], 1);
    float4 gA, gB, gC;
    gA.x = ux; gA.y = uy; gA.z = uz; gA.w = __int_as_float(nj);
    gB.x = cut * vp7;
    gB.y = cut * 7.f  * ur  * vp6;
    gB.z = cut * 21.f * up2 * vp5;
    gB.w = cut * 35.f * up3 * vp4;
    gC.x = cut * 35.f * up4 * vp3;
    gC.y = cut * 21.f * up5 * vp2;
    gC.z = cut * 7.f  * up6 * vr;
    gC.w = cut * up7;
    geo[(size_t)3 * p + 0] = gA;
    geo[(size_t)3 * p + 1] = gB;
    geo[(size_t)3 * p + 2] = gC;
}

// one wave64 per node (persistent stride); half-wave = one edge stream, lane&31 = feature.
// Deep pipeline: gA 2 iterations ahead (so next xe addresses are ready at iter start),
// gB/gC and xe 1 iteration ahead.
template<int LAST>
__global__ __launch_bounds__(256) void gather_kernel(const float4* __restrict__ geo,
                                                     const float* __restrict__ rw_iter, // [3][8][32]
                                                     const float* __restrict__ x,
                                                     const int* __restrict__ offs,
                                                     float* __restrict__ m) {
    const int NWAVES = 1024 * 4;
    int lane = threadIdx.x & 63;
    int wid  = threadIdx.x >> 6;
    int half = lane >> 5;
    int f    = lane & 31;
    int gw   = blockIdx.x * 4 + wid;

    float rwv[24];
    #pragma unroll
    for (int lb = 0; lb < 24; ++lb) rwv[lb] = rw_iter[lb * F + f];
    if (LAST) {
        #pragma unroll
        for (int lb = 8; lb < 16; ++lb) rwv[lb] *= C13;
        #pragma unroll
        for (int lb = 16; lb < 24; ++lb) rwv[lb] *= C15;
    }

    constexpr int NACC = LAST ? 1 : KCH;

    for (int n = gw; n < NN; n += NWAVES) {
        int start = offs[n], end = offs[n + 1];

        float acc[NACC];
        #pragma unroll
        for (int a = 0; a < NACC; ++a) acc[a] = 0.f;

        int t = start + half;
        float4 gA_c = {}, gB_c = {}, gC_c = {}, gA_n = {};
        float xe_c[9];
        #pragma unroll
        for (int a = 0; a < 9; ++a) xe_c[a] = 0.f;

        if (t < end) {
            gA_c = geo[(size_t)3 * t + 0];
            gB_c = geo[(size_t)3 * t + 1];
            gC_c = geo[(size_t)3 * t + 2];
            int njc = __float_as_int(gA_c.w);
            const float* xp = x + (size_t)njc * KCH * F + f;
            #pragma unroll
            for (int a = 0; a < 9; ++a) xe_c[a] = xp[a * F];
        }
        if (t + 2 < end) gA_n = geo[(size_t)3 * (t + 2) + 0];

        while (t < end) {
            int tn = t + 2, tf = t + 4;
            bool hn = tn < end, hf = tf < end;

            float4 gA_f = {}, gB_n = {}, gC_n = {};
            float xe_n[9];
            if (hf) gA_f = geo[(size_t)3 * tf + 0];
            if (hn) {
                gB_n = geo[(size_t)3 * tn + 1];
                gC_n = geo[(size_t)3 * tn + 2];
                int njn = __float_as_int(gA_n.w);
                const float* xp = x + (size_t)njn * KCH * F + f;
                #pragma unroll
                for (int a = 0; a < 9; ++a) xe_n[a] = xp[a * F];
            }

            // ---- compute edge t from *_c state ----
            float ux = gA_c.x, uy = gA_c.y, uz = gA_c.z;
            float g0, g1, g2;
            g0 = gB_c.x * rwv[0];
            g0 = fmaf(gB_c.y, rwv[1], g0); g0 = fmaf(gB_c.z, rwv[2], g0); g0 = fmaf(gB_c.w, rwv[3], g0);
            g0 = fmaf(gC_c.x, rwv[4], g0); g0 = fmaf(gC_c.y, rwv[5], g0); g0 = fmaf(gC_c.z, rwv[6], g0);
            g0 = fmaf(gC_c.w, rwv[7], g0);
            g1 = gB_c.x * rwv[8];
            g1 = fmaf(gB_c.y, rwv[9],  g1); g1 = fmaf(gB_c.z, rwv[10], g1); g1 = fmaf(gB_c.w, rwv[11], g1);
            g1 = fmaf(gC_c.x, rwv[12], g1); g1 = fmaf(gC_c.y, rwv[13], g1); g1 = fmaf(gC_c.z, rwv[14], g1);
            g1 = fmaf(gC_c.w, rwv[15], g1);
            g2 = gB_c.x * rwv[16];
            g2 = fmaf(gB_c.y, rwv[17], g2); g2 = fmaf(gB_c.z, rwv[18], g2); g2 = fmaf(gB_c.w, rwv[19], g2);
            g2 = fmaf(gC_c.x, rwv[20], g2); g2 = fmaf(gC_c.y, rwv[21], g2); g2 = fmaf(gC_c.z, rwv[22], g2);
            g2 = fmaf(gC_c.w, rwv[23], g2);

            if (LAST) {
                // y0 with C13/C15 folded into g1/g2 via rwv pre-scale
                float dot1 = uy * xe_c[1];
                dot1 = fmaf(uz, xe_c[2], dot1);
                dot1 = fmaf(ux, xe_c[3], dot1);
                float Y4 = S3 * ux * uy, Y5 = S3 * uy * uz, Y7 = S3 * ux * uz;
                float Y6 = fmaf(1.5f * uz, uz, -0.5f);
                float Y8 = 0.5f * S3 * (ux * ux - uy * uy);
                float dot2 = Y4 * xe_c[4];
                dot2 = fmaf(Y5, xe_c[5], dot2);
                dot2 = fmaf(Y6, xe_c[6], dot2);
                dot2 = fmaf(Y7, xe_c[7], dot2);
                dot2 = fmaf(Y8, xe_c[8], dot2);
                acc[0] = fmaf(g0, xe_c[0], acc[0]);
                acc[0] = fmaf(g1, dot1, acc[0]);
                acc[0] = fmaf(g2, dot2, acc[0]);
            } else {
                float s2 = S3 * g2;
                float w[9];
                w[0] = g0;
                w[1] = uy * g1; w[2] = uz * g1; w[3] = ux * g1;
                w[4] = s2 * ux * uy;
                w[5] = s2 * uy * uz;
                w[6] = fmaf(1.5f * uz, uz, -0.5f) * g2;
                w[7] = s2 * ux * uz;
                w[8] = 0.5f * s2 * (ux * ux - uy * uy);

                float d0 = xe_c[0]*w[0], d1 = xe_c[1]*w[1], d2 = xe_c[2]*w[2], d3 = xe_c[3]*w[3];
                float d4 = xe_c[4]*w[4], d5 = xe_c[5]*w[5], d6 = xe_c[6]*w[6], d7 = xe_c[7]*w[7];
                float d8 = xe_c[8]*w[8];

                acc[0] += d0 + C13 * (d1 + d2 + d3) + C15 * (d4 + d5 + d6 + d7 + d8);
                #define T(a, b) (xe_c[a] * w[b] + xe_c[b] * w[a])
                acc[1] += T(0,1) - C15 * T(1,6) - S35 * T(1,8) + S35 * T(2,5) + S35 * T(3,4);
                acc[2] += T(0,2) + S35 * T(1,5) + C25 * T(2,6) + S35 * T(3,7);
                acc[3] += T(0,3) + S35 * T(1,4) + S35 * T(2,7) - C15 * T(3,6) + S35 * T(3,8);
                acc[4] += T(0,4) + IS3 * T(1,3) - C27 * T(4,6) + S37 * T(5,7);
                acc[5] += T(0,5) + IS3 * T(1,2) + S37 * T(4,7) + C17 * T(5,6) - S37 * T(5,8);
                acc[6] += T(0,6) - C13 * d1 + C23 * d2 - C13 * d3
                        - C27 * d4 + C17 * d5 + C27 * d6 + C17 * d7 - C27 * d8;
                acc[7] += T(0,7) + IS3 * T(2,3) + S37 * T(4,5) + C17 * T(6,7) + S37 * T(7,8);
                acc[8] += T(0,8) - IS3 * d1 + IS3 * d3 - S37 * d5 + S37 * d7 - C27 * T(6,8);
                #undef T
            }

            // rotate pipeline
            gA_c = gA_n; gA_n = gA_f;
            gB_c = gB_n; gC_c = gC_n;
            #pragma unroll
            for (int a = 0; a < 9; ++a) xe_c[a] = xe_n[a];
            t = tn;
        }

        #pragma unroll
        for (int a = 0; a < NACC; ++a) acc[a] += __shfl_xor(acc[a], 32);

        if (half == 0) {
            if (LAST) {
                m[(size_t)n * F + f] = acc[0];
            } else {
                float* mp = m + (size_t)n * KCH * F + f;
                #pragma unroll
                for (int a = 0; a < KCH; ++a) mp[a * F] = acc[a];
            }
        }
    }
}

// one thread per (node, k) row; weights fetched as wave-uniform scalar loads
__global__ __launch_bounds__(256) void node_full(float* __restrict__ x,
                                                 const float* __restrict__ m,
                                                 const float* __restrict__ w1,
                                                 const float* __restrict__ b1,
                                                 const float* __restrict__ w2,
                                                 const float* __restrict__ b2) {
    __shared__ float gs[28][33];
    int t = threadIdx.x;
    int slot = t / 9, k = t - slot * 9;
    int n = blockIdx.x * 28 + slot;
    bool valid = (t < 252) && (n < NN);

    float h[F], o1[F];
    if (valid) {
        const float4* xp = (const float4*)(x + ((size_t)n * KCH + k) * F);
        const float4* mp = (const float4*)(m + ((size_t)n * KCH + k) * F);
        #pragma unroll
        for (int j = 0; j < 8; ++j) {
            float4 a = xp[j], b = mp[j];
            h[4 * j + 0] = a.x + b.x; h[4 * j + 1] = a.y + b.y;
            h[4 * j + 2] = a.z + b.z; h[4 * j + 3] = a.w + b.w;
        }
        #pragma unroll
        for (int fo = 0; fo < F; ++fo) {
            float s = 0.f;
            #pragma unroll
            for (int fi = 0; fi < F; ++fi) s = fmaf(h[fi], w1[fi * F + fo], s);
            o1[fo] = s;
        }
        if (k == 0) {
            #pragma unroll
            for (int j = 0; j < F; ++j) {
                o1[j] += b1[j];
                gs[slot][j] = 1.0f / (1.0f + expf(-o1[j]));
            }
        }
    }
    __syncthreads();
    if (valid) {
        #pragma unroll
        for (int j = 0; j < F; ++j) h[j] = o1[j] * gs[slot][j];
        #pragma unroll
        for (int fo = 0; fo < F; ++fo) {
            float s = (k == 0) ? b2[fo] : 0.f;
            #pragma unroll
            for (int fi = 0; fi < F; ++fi) s = fmaf(h[fi], w2[fi * F + fo], s);
            o1[fo] = s;
        }
        float4* xw = (float4*)(x + ((size_t)n * KCH + k) * F);
        #pragma unroll
        for (int j = 0; j < 8; ++j) {
            float4 a = xw[j];
            a.x += o1[4 * j + 0]; a.y += o1[4 * j + 1];
            a.z += o1[4 * j + 2]; a.w += o1[4 * j + 3];
            xw[j] = a;
        }
    }
}

__global__ __launch_bounds__(256) void node_last(const float* __restrict__ x,
                                                 const float* __restrict__ m1,
                                                 const float* __restrict__ w1,
                                                 const float* __restrict__ b1,
                                                 const float* __restrict__ w2,
                                                 const float* __restrict__ b2,
                                                 float* __restrict__ out) {
    int n = blockIdx.x * 256 + threadIdx.x;
    if (n >= NN) return;
    float h[F], o1[F];
    const float4* xp = (const float4*)(x + (size_t)n * KCH * F);   // row k=0
    const float4* mp = (const float4*)(m1 + (size_t)n * F);
    #pragma unroll
    for (int j = 0; j < 8; ++j) {
        float4 a = xp[j], b = mp[j];
        h[4 * j + 0] = a.x + b.x; h[4 * j + 1] = a.y + b.y;
        h[4 * j + 2] = a.z + b.z; h[4 * j + 3] = a.w + b.w;
    }
    #pragma unroll
    for (int fo = 0; fo < F; ++fo) {
        float s = 0.f;
        #pragma unroll
        for (int fi = 0; fi < F; ++fi) s = fmaf(h[fi], w1[fi * F + fo], s);
        s += b1[fo];
        o1[fo] = s;
    }
    #pragma unroll
    for (int j = 0; j < F; ++j) {
        float g = 1.0f / (1.0f + expf(-o1[j]));
        h[j] = o1[j] * g;
    }
    #pragma unroll
    for (int fo = 0; fo < F; ++fo) {
        float s = b2[fo];
        #pragma unroll
        for (int fi = 0; fi < F; ++fi) s = fmaf(h[fi], w2[fi * F + fo], s);
        o1[fo] = s;
    }
    #pragma unroll
    for (int j = 0; j < F; ++j)
        out[(size_t)n * F + j] = x[(size_t)n * KCH * F + j] + o1[j];
}

extern "C" void kernel_launch(void* const* d_in, const int* in_sizes, int n_in,
                              void* d_out, int out_size, void* d_ws, size_t ws_size,
                              hipStream_t stream) {
    (void)in_sizes; (void)n_in; (void)out_size; (void)ws_size;
    const float* dr    = (const float*)d_in[0];
    const float* embed = (const float*)d_in[1];
    const float* rad_w = (const float*)d_in[2];
    const float* d1w   = (const float*)d_in[3];
    const float* d1b   = (const float*)d_in[4];
    const float* d2w   = (const float*)d_in[5];
    const float* d2b   = (const float*)d_in[6];
    const int*   Z     = (const int*)d_in[7];
    const int*   nidx  = (const int*)d_in[8];
    const int* idx_i = nidx;
    const int* idx_j = nidx + NE;

    float* x = (float*)d_ws;
    float* m = x + (size_t)NN * KCH * F;
    int*   offs = (int*)(m + (size_t)NN * KCH * F);   // NN+1
    int*   head = offs + (NN + 1);                    // NN
    int*   cnt  = head + NN;                          // NN (+pad to 16B)
    float4* geo = (float4*)(cnt + NN + 3);            // 3*NE float4 (live-compacted)
    float* outp = (float*)d_out;

    // CSR build with dead-edge filtering + geometry precompute
    hipMemsetAsync(cnt, 0, NN * sizeof(int), stream);
    hist_kernel<<<(NE + 255) / 256, 256, 0, stream>>>(idx_i, idx_j, dr, cnt);
    scan_kernel<<<1, SCAN_T, 0, stream>>>(cnt, offs, head);
    fill_kernel<<<(NE + 255) / 256, 256, 0, stream>>>(idx_i, idx_j, dr, head, geo);

    init_x<<<(NN * F + 255) / 256, 256, 0, stream>>>(embed, Z, x);

    for (int i = 0; i < 3; ++i) {
        const float* rwi = rad_w + (size_t)i * 3 * 8 * F;
        const float* w1 = d1w + (size_t)i * F * F;
        const float* b1 = d1b + (size_t)i * F;
        const float* w2 = d2w + (size_t)i * F * F;
        const float* b2 = d2b + (size_t)i * F;
        if (i < 2) {
            gather_kernel<0><<<1024, 256, 0, stream>>>(geo, rwi, x, offs, m);
            node_full<<<(NN + 27) / 28, 256, 0, stream>>>(x, m, w1, b1, w2, b2);
        } else {
            gather_kernel<1><<<1024, 256, 0, stream>>>(geo, rwi, x, offs, m);
            node_last<<<(NN + 255) / 256, 256, 0, stream>>>(x, m, w1, b1, w2, b2, outp);
        }
    }
}

// Round 5
// 699.425 us; speedup vs baseline: 1.3056x; 1.3056x over previous
//
#include <hip/hip_runtime.h>
#include <hip/hip_fp16.h>
#include <math.h>

#define NN 50000
#define NE 640000
#define F  32
#define KCH 9
#define CUT 5.0f

#define C13 (1.0f/3.0f)
#define C23 (2.0f/3.0f)
#define C15 0.2f
#define C25 0.4f
#define C17 (1.0f/7.0f)
#define C27 (2.0f/7.0f)
#define IS3 0.5773502691896258f
#define S35 0.3464101615137755f
#define S37 0.2474358296526968f
#define S3  1.7320508075688772f

// xh layout: per node 32 f-rows of 12 halves (9 used) = 768 B/node, 24 B/lane
#define XH_NODE_B 768

union U2H { unsigned int u; __half2 h; };

__device__ __forceinline__ unsigned int pack2(float a, float b) {
    U2H c; c.h = __floats2half2_rn(a, b); return c.u;
}
__device__ __forceinline__ float2 unpack2(unsigned int u) {
    U2H c; c.u = u; return __half22float2(c.h);
}

__global__ __launch_bounds__(256) void init_x(const float* __restrict__ embed,
                                              const int* __restrict__ Z,
                                              float* __restrict__ x,
                                              char* __restrict__ xh) {
    int idx = blockIdx.x * 256 + threadIdx.x;   // n*32 + f
    int n = idx >> 5, f = idx & 31;
    float v = embed[Z[n] * F + f];
    float* xp = x + (size_t)n * KCH * F + f;
    xp[0] = v;
    #pragma unroll
    for (int a = 1; a < KCH; ++a) xp[a * F] = 0.f;
    char* bp = xh + (size_t)n * XH_NODE_B + f * 24;
    uint2 u0; u0.x = pack2(v, 0.f); u0.y = 0u;
    uint2 zz; zz.x = 0u; zz.y = 0u;
    *(uint2*)bp = u0;
    *(uint2*)(bp + 8) = zz;
    *(uint2*)(bp + 16) = zz;
}

__global__ __launch_bounds__(256) void hist_kernel(const int* __restrict__ idx_i,
                                                   const int* __restrict__ idx_j,
                                                   const float* __restrict__ dr,
                                                   int* __restrict__ cnt) {
    int e = blockIdx.x * 256 + threadIdx.x;
    if (e >= NE) return;
    int ni = idx_i[e], nj = idx_j[e];
    float dx = dr[3 * e + 0], dy = dr[3 * e + 1], dz = dr[3 * e + 2];
    float r2 = fmaf(dx, dx, fmaf(dy, dy, dz * dz));
    if (ni != nj && r2 < CUT * CUT) atomicAdd(&cnt[ni], 1);
}

#define SCAN_T 1024
#define SCAN_C ((NN + SCAN_T - 1) / SCAN_T)

__global__ __launch_bounds__(SCAN_T) void scan_kernel(const int* __restrict__ cnt,
                                                      int* __restrict__ offs,
                                                      int* __restrict__ head) {
    __shared__ int ps[SCAN_T];
    int t = threadIdx.x;
    int b = t * SCAN_C;
    int e = min(b + SCAN_C, NN);
    int s = 0;
    for (int i = b; i < e; ++i) s += cnt[i];
    ps[t] = s;
    __syncthreads();
    for (int off = 1; off < SCAN_T; off <<= 1) {
        int v = (t >= off) ? ps[t - off] : 0;
        __syncthreads();
        ps[t] += v;
        __syncthreads();
    }
    int run = (t == 0) ? 0 : ps[t - 1];
    for (int i = b; i < e; ++i) { int c = cnt[i]; offs[i] = run; head[i] = run; run += c; }
    if (t == SCAN_T - 1) offs[NN] = ps[SCAN_T - 1];
}

// gA = {ux,uy,uz,bits(nj)}, gB = {rc0..3}, gC = {rc4..7}
__global__ __launch_bounds__(256) void fill_kernel(const int* __restrict__ idx_i,
                                                   const int* __restrict__ idx_j,
                                                   const float* __restrict__ dr,
                                                   int* __restrict__ head,
                                                   float4* __restrict__ geo) {
    int e = blockIdx.x * 256 + threadIdx.x;
    if (e >= NE) return;
    int ni = idx_i[e], nj = idx_j[e];
    float dx = dr[3 * e + 0], dy = dr[3 * e + 1], dz = dr[3 * e + 2];
    float r2 = fmaf(dx, dx, fmaf(dy, dy, dz * dz));
    if (!(ni != nj && r2 < CUT * CUT)) return;

    float r = sqrtf(r2);
    float inv = 1.0f / fmaxf(r, 1e-9f);
    float ux = dx * inv, uy = dy * inv, uz = dz * inv;

    float cut = expf(-r2 / fmaxf(CUT * CUT - r2, 1e-12f));
    float ur = r / (1.0f + r), vr = 1.0f - ur;
    float up2 = ur*ur, up3 = up2*ur, up4 = up3*ur, up5 = up4*ur, up6 = up5*ur, up7 = up6*ur;
    float vp2 = vr*vr, vp3 = vp2*vr, vp4 = vp3*vr, vp5 = vp4*vr, vp6 = vp5*vr, vp7 = vp6*vr;

    int p = atomicAdd(&head[ni], 1);
    float4 gA, gB, gC;
    gA.x = ux; gA.y = uy; gA.z = uz; gA.w = __int_as_float(nj);
    gB.x = cut * vp7;
    gB.y = cut * 7.f  * ur  * vp6;
    gB.z = cut * 21.f * up2 * vp5;
    gB.w = cut * 35.f * up3 * vp4;
    gC.x = cut * 35.f * up4 * vp3;
    gC.y = cut * 21.f * up5 * vp2;
    gC.z = cut * 7.f  * up6 * vr;
    gC.w = cut * up7;
    geo[(size_t)3 * p + 0] = gA;
    geo[(size_t)3 * p + 1] = gB;
    geo[(size_t)3 * p + 2] = gC;
}

// one wave64 per node; half-wave = one edge stream, lane&31 = feature.
// xh prefetched depth-2 (nj known one iteration early), geo depth-1, branch-free clamps.
template<int LAST>
__global__ __launch_bounds__(256) void gather_kernel(const float4* __restrict__ geo,
                                                     const char* __restrict__ xh,
                                                     const float* __restrict__ rw_iter,
                                                     const int* __restrict__ offs,
                                                     float* __restrict__ m) {
    const int NWAVES = 2048 * 4;
    int lane = threadIdx.x & 63;
    int wid  = threadIdx.x >> 6;
    int half = lane >> 5;
    int f    = lane & 31;
    int gw   = blockIdx.x * 4 + wid;

    float rwv[24];
    #pragma unroll
    for (int lb = 0; lb < 24; ++lb) rwv[lb] = rw_iter[lb * F + f];
    if (LAST) {
        #pragma unroll
        for (int lb = 8; lb < 16; ++lb) rwv[lb] *= C13;
        #pragma unroll
        for (int lb = 16; lb < 24; ++lb) rwv[lb] *= C15;
    }

    constexpr int NACC = LAST ? 1 : KCH;

    for (int n = gw; n < NN; n += NWAVES) {
        int start = offs[n], end = offs[n + 1];

        float acc[NACC];
        #pragma unroll
        for (int a = 0; a < NACC; ++a) acc[a] = 0.f;

        int t = start + half;
        float4 gA_c = {}, gB_c = {}, gC_c = {}, gA_n = {};
        uint2 xa = {}, xb = {};
        unsigned int xc = 0;

        if (t < end) {
            gA_c = geo[(size_t)3 * t + 0];
            gB_c = geo[(size_t)3 * t + 1];
            gC_c = geo[(size_t)3 * t + 2];
            int njc = __float_as_int(gA_c.w);
            const char* bp = xh + (size_t)njc * XH_NODE_B + f * 24;
            xa = *(const uint2*)bp;
            xb = *(const uint2*)(bp + 8);
            xc = *(const unsigned int*)(bp + 16);
            int t2 = (t + 2 < end) ? t + 2 : t;
            gA_n = geo[(size_t)3 * t2 + 0];
        }

        while (t < end) {
            int tn = t + 2;
            int tnc = (tn < end) ? tn : t;          // clamped, branch-free
            int tfc = (tn + 2 < end) ? tn + 2 : tnc;

            float4 gA_f = geo[(size_t)3 * tfc + 0];
            float4 gB_n = geo[(size_t)3 * tnc + 1];
            float4 gC_n = geo[(size_t)3 * tnc + 2];
            int njn = __float_as_int(gA_n.w);
            const char* bp = xh + (size_t)njn * XH_NODE_B + f * 24;
            uint2 na = *(const uint2*)bp;
            uint2 nb = *(const uint2*)(bp + 8);
            unsigned int nc = *(const unsigned int*)(bp + 16);

            // unpack current edge's xe
            float xe[9];
            {
                float2 p;
                p = unpack2(xa.x); xe[0] = p.x; xe[1] = p.y;
                p = unpack2(xa.y); xe[2] = p.x; xe[3] = p.y;
                p = unpack2(xb.x); xe[4] = p.x; xe[5] = p.y;
                p = unpack2(xb.y); xe[6] = p.x; xe[7] = p.y;
                p = unpack2(xc);   xe[8] = p.x;
            }

            float ux = gA_c.x, uy = gA_c.y, uz = gA_c.z;
            float g0, g1, g2;
            g0 = gB_c.x * rwv[0];
            g0 = fmaf(gB_c.y, rwv[1], g0); g0 = fmaf(gB_c.z, rwv[2], g0); g0 = fmaf(gB_c.w, rwv[3], g0);
            g0 = fmaf(gC_c.x, rwv[4], g0); g0 = fmaf(gC_c.y, rwv[5], g0); g0 = fmaf(gC_c.z, rwv[6], g0);
            g0 = fmaf(gC_c.w, rwv[7], g0);
            g1 = gB_c.x * rwv[8];
            g1 = fmaf(gB_c.y, rwv[9],  g1); g1 = fmaf(gB_c.z, rwv[10], g1); g1 = fmaf(gB_c.w, rwv[11], g1);
            g1 = fmaf(gC_c.x, rwv[12], g1); g1 = fmaf(gC_c.y, rwv[13], g1); g1 = fmaf(gC_c.z, rwv[14], g1);
            g1 = fmaf(gC_c.w, rwv[15], g1);
            g2 = gB_c.x * rwv[16];
            g2 = fmaf(gB_c.y, rwv[17], g2); g2 = fmaf(gB_c.z, rwv[18], g2); g2 = fmaf(gB_c.w, rwv[19], g2);
            g2 = fmaf(gC_c.x, rwv[20], g2); g2 = fmaf(gC_c.y, rwv[21], g2); g2 = fmaf(gC_c.z, rwv[22], g2);
            g2 = fmaf(gC_c.w, rwv[23], g2);

            if (LAST) {
                float dot1 = uy * xe[1];
                dot1 = fmaf(uz, xe[2], dot1);
                dot1 = fmaf(ux, xe[3], dot1);
                float Y4 = S3 * ux * uy, Y5 = S3 * uy * uz, Y7 = S3 * ux * uz;
                float Y6 = fmaf(1.5f * uz, uz, -0.5f);
                float Y8 = 0.5f * S3 * (ux * ux - uy * uy);
                float dot2 = Y4 * xe[4];
                dot2 = fmaf(Y5, xe[5], dot2);
                dot2 = fmaf(Y6, xe[6], dot2);
                dot2 = fmaf(Y7, xe[7], dot2);
                dot2 = fmaf(Y8, xe[8], dot2);
                acc[0] = fmaf(g0, xe[0], acc[0]);
                acc[0] = fmaf(g1, dot1, acc[0]);
                acc[0] = fmaf(g2, dot2, acc[0]);
            } else {
                float s2 = S3 * g2;
                float w[9];
                w[0] = g0;
                w[1] = uy * g1; w[2] = uz * g1; w[3] = ux * g1;
                w[4] = s2 * ux * uy;
                w[5] = s2 * uy * uz;
                w[6] = fmaf(1.5f * uz, uz, -0.5f) * g2;
                w[7] = s2 * ux * uz;
                w[8] = 0.5f * s2 * (ux * ux - uy * uy);

                float d0 = xe[0]*w[0], d1 = xe[1]*w[1], d2 = xe[2]*w[2], d3 = xe[3]*w[3];
                float d4 = xe[4]*w[4], d5 = xe[5]*w[5], d6 = xe[6]*w[6], d7 = xe[7]*w[7];
                float d8 = xe[8]*w[8];

                acc[0] += d0 + C13 * (d1 + d2 + d3) + C15 * (d4 + d5 + d6 + d7 + d8);
                #define T(a, b) (xe[a] * w[b] + xe[b] * w[a])
                acc[1] += T(0,1) - C15 * T(1,6) - S35 * T(1,8) + S35 * T(2,5) + S35 * T(3,4);
                acc[2] += T(0,2) + S35 * T(1,5) + C25 * T(2,6) + S35 * T(3,7);
                acc[3] += T(0,3) + S35 * T(1,4) + S35 * T(2,7) - C15 * T(3,6) + S35 * T(3,8);
                acc[4] += T(0,4) + IS3 * T(1,3) - C27 * T(4,6) + S37 * T(5,7);
                acc[5] += T(0,5) + IS3 * T(1,2) + S37 * T(4,7) + C17 * T(5,6) - S37 * T(5,8);
                acc[6] += T(0,6) - C13 * d1 + C23 * d2 - C13 * d3
                        - C27 * d4 + C17 * d5 + C27 * d6 + C17 * d7 - C27 * d8;
                acc[7] += T(0,7) + IS3 * T(2,3) + S37 * T(4,5) + C17 * T(6,7) + S37 * T(7,8);
                acc[8] += T(0,8) - IS3 * d1 + IS3 * d3 - S37 * d5 + S37 * d7 - C27 * T(6,8);
                #undef T
            }

            gA_c = gA_n; gA_n = gA_f;
            gB_c = gB_n; gC_c = gC_n;
            xa = na; xb = nb; xc = nc;
            t = tn;
        }

        #pragma unroll
        for (int a = 0; a < NACC; ++a) acc[a] += __shfl_xor(acc[a], 32);

        if (half == 0) {
            if (LAST) {
                m[(size_t)n * F + f] = acc[0];
            } else {
                float* mp = m + (size_t)n * KCH * F + f;
                #pragma unroll
                for (int a = 0; a < KCH; ++a) mp[a * F] = acc[a];
            }
        }
    }
}

// thread = (node, f). LDS tile for cross-feature mixing; per-lane weight columns.
// Writes updated f32 x AND packed fp16 xh (thread owns all 9 k for its f).
__global__ __launch_bounds__(256) void node_full(float* __restrict__ x,
                                                 const float* __restrict__ m,
                                                 char* __restrict__ xh,
                                                 const float* __restrict__ w1,
                                                 const float* __restrict__ b1,
                                                 const float* __restrict__ w2,
                                                 const float* __restrict__ b2) {
    __shared__ float tile[8][KCH][F];
    int nl = threadIdx.x >> 5, f = threadIdx.x & 31;
    int n = blockIdx.x * 8 + nl;

    float w1c[F];
    #pragma unroll
    for (int fi = 0; fi < F; ++fi) w1c[fi] = w1[fi * F + f];

    float xk[KCH];
    #pragma unroll
    for (int k = 0; k < KCH; ++k) {
        xk[k] = x[((size_t)n * KCH + k) * F + f];
        tile[nl][k][f] = xk[k] + m[((size_t)n * KCH + k) * F + f];
    }
    __syncthreads();

    float o1[KCH];
    #pragma unroll
    for (int k = 0; k < KCH; ++k) {
        float s = 0.f;
        #pragma unroll
        for (int fi = 0; fi < F; ++fi) s = fmaf(tile[nl][k][fi], w1c[fi], s);
        o1[k] = s;
    }
    o1[0] += b1[f];
    float gate = 1.0f / (1.0f + expf(-o1[0]));
    __syncthreads();
    #pragma unroll
    for (int k = 0; k < KCH; ++k) tile[nl][k][f] = o1[k] * gate;
    __syncthreads();

    float w2c[F];
    #pragma unroll
    for (int fi = 0; fi < F; ++fi) w2c[fi] = w2[fi * F + f];

    float xn[KCH];
    #pragma unroll
    for (int k = 0; k < KCH; ++k) {
        float s = (k == 0) ? b2[f] : 0.f;
        #pragma unroll
        for (int fi = 0; fi < F; ++fi) s = fmaf(tile[nl][k][fi], w2c[fi], s);
        xn[k] = xk[k] + s;
        x[((size_t)n * KCH + k) * F + f] = xn[k];
    }

    char* bp = xh + (size_t)n * XH_NODE_B + f * 24;
    uint2 u0, u1, u2;
    u0.x = pack2(xn[0], xn[1]); u0.y = pack2(xn[2], xn[3]);
    u1.x = pack2(xn[4], xn[5]); u1.y = pack2(xn[6], xn[7]);
    u2.x = pack2(xn[8], 0.f);   u2.y = 0u;
    *(uint2*)bp = u0;
    *(uint2*)(bp + 8) = u1;
    *(uint2*)(bp + 16) = u2;
}

__global__ __launch_bounds__(256) void node_last(const float* __restrict__ x,
                                                 const float* __restrict__ m1,
                                                 const float* __restrict__ w1,
                                                 const float* __restrict__ b1,
                                                 const float* __restrict__ w2,
                                                 const float* __restrict__ b2,
                                                 float* __restrict__ out) {
    __shared__ float tile[8][F];
    int nl = threadIdx.x >> 5, f = threadIdx.x & 31;
    int n = blockIdx.x * 8 + nl;

    float w1c[F];
    #pragma unroll
    for (int fi = 0; fi < F; ++fi) w1c[fi] = w1[fi * F + f];

    float x0 = x[(size_t)n * KCH * F + f];
    tile[nl][f] = x0 + m1[(size_t)n * F + f];
    __syncthreads();
    float s = 0.f;
    #pragma unroll
    for (int fi = 0; fi < F; ++fi) s = fmaf(tile[nl][fi], w1c[fi], s);
    s += b1[f];
    float gate = 1.0f / (1.0f + expf(-s));
    float h2 = s * gate;
    __syncthreads();
    tile[nl][f] = h2;
    __syncthreads();
    float w2c[F];
    #pragma unroll
    for (int fi = 0; fi < F; ++fi) w2c[fi] = w2[fi * F + f];
    float o = b2[f];
    #pragma unroll
    for (int fi = 0; fi < F; ++fi) o = fmaf(tile[nl][fi], w2c[fi], o);
    out[(size_t)n * F + f] = x0 + o;
}

extern "C" void kernel_launch(void* const* d_in, const int* in_sizes, int n_in,
                              void* d_out, int out_size, void* d_ws, size_t ws_size,
                              hipStream_t stream) {
    (void)in_sizes; (void)n_in; (void)out_size; (void)ws_size;
    const float* dr    = (const float*)d_in[0];
    const float* embed = (const float*)d_in[1];
    const float* rad_w = (const float*)d_in[2];
    const float* d1w   = (const float*)d_in[3];
    const float* d1b   = (const float*)d_in[4];
    const float* d2w   = (const float*)d_in[5];
    const float* d2b   = (const float*)d_in[6];
    const int*   Z     = (const int*)d_in[7];
    const int*   nidx  = (const int*)d_in[8];
    const int* idx_i = nidx;
    const int* idx_j = nidx + NE;

    // workspace layout (all 16B-aligned)
    float* x = (float*)d_ws;                                  // 14.4M f32
    float* m = x + (size_t)NN * KCH * F;                      // 14.4M f32
    char*  xh = (char*)(m + (size_t)NN * KCH * F);            // NN*768 B
    float4* geo = (float4*)(xh + (size_t)NN * XH_NODE_B);     // 3*(NE+1) float4
    int* offs = (int*)(geo + (size_t)3 * (NE + 1));           // NN+1
    int* head = offs + (NN + 1);                              // NN
    int* cnt  = head + NN;                                    // NN
    float* outp = (float*)d_out;

    hipMemsetAsync(cnt, 0, NN * sizeof(int), stream);
    hist_kernel<<<(NE + 255) / 256, 256, 0, stream>>>(idx_i, idx_j, dr, cnt);
    scan_kernel<<<1, SCAN_T, 0, stream>>>(cnt, offs, head);
    fill_kernel<<<(NE + 255) / 256, 256, 0, stream>>>(idx_i, idx_j, dr, head, geo);

    init_x<<<NN * F / 256, 256, 0, stream>>>(embed, Z, x, xh);

    for (int i = 0; i < 3; ++i) {
        const float* rwi = rad_w + (size_t)i * 3 * 8 * F;
        const float* w1 = d1w + (size_t)i * F * F;
        const float* b1 = d1b + (size_t)i * F;
        const float* w2 = d2w + (size_t)i * F * F;
        const float* b2 = d2b + (size_t)i * F;
        if (i < 2) {
            gather_kernel<0><<<2048, 256, 0, stream>>>(geo, xh, rwi, offs, m);
            node_full<<<NN / 8, 256, 0, stream>>>(x, m, xh, w1, b1, w2, b2);
        } else {
            gather_kernel<1><<<2048, 256, 0, stream>>>(geo, xh, rwi, offs, m);
            node_last<<<NN / 8, 256, 0, stream>>>(x, m, w1, b1, w2, b2, outp);
        }
    }
}